// Round 14
// baseline (51.914 us; speedup 1.0000x reference)
//
#include <hip/hip_runtime.h>
#include <hip/hip_bf16.h>

// CatEmbedder: B=4096, L=128, D=64, PROBE=1 -> 1/129, ALPHA=0.5
// Histogram formulation: C[b,k] = count of k in idx[b,:]  (<=128, exact bf16)
//   s[b]  = C[b]@emb,  sq[b] = C[b]@emb^2        (MFMA, transposed form)
//   u[b]  = (s[b]@acc_w)/129 + acc_b             (MFMA)
//   loc0  = 0.5*(s^2 - sq); loc2 = MLP(loc0)     (MFMA)
//   g0    = relu(u[b] + tsup[idx]); g2 = MLP(g0) (MFMA, transposed)
//   out   = (0.5*W1)·g1 + 0.5*(gb1 + lb1 + loc2) [prescaled]
// R14: fused kernel VGPR diet -> 16 waves/CU: launch_bounds(256,4); tsup read
// direct from L1-resident global (no LDS staging); w0/w1 frags re-read per
// tile from L1-resident fragtab (short live ranges). Combined = R10's.

typedef __attribute__((ext_vector_type(8))) short bf16x8;
typedef __attribute__((ext_vector_type(4))) float f32x4;
typedef __attribute__((ext_vector_type(2))) unsigned int u32x2;

#define RECIP129 (1.0f/129.0f)

static __device__ __forceinline__ unsigned int cvt_pk_bf16(float lo, float hi){
  unsigned int r;
  asm("v_cvt_pk_bf16_f32 %0, %1, %2" : "=v"(r) : "v"(lo), "v"(hi));
  return r;
}
static __device__ __forceinline__ bf16x8 pack8(const float* v){
  uint4 p;
  p.x = cvt_pk_bf16(v[0], v[1]); p.y = cvt_pk_bf16(v[2], v[3]);
  p.z = cvt_pk_bf16(v[4], v[5]); p.w = cvt_pk_bf16(v[6], v[7]);
  return __builtin_bit_cast(bf16x8, p);
}

// ---------------- kernel A: perb (0-255) | tsupb (256-263) | gwfrag (264) ---
__global__ __launch_bounds__(256) void combined_kernel(
    const int*   __restrict__ cat,
    const float* __restrict__ emb,
    const float* __restrict__ acc_w,
    const float* __restrict__ acc_b,
    const float* __restrict__ lw,
    const float* __restrict__ lb,
    const float* __restrict__ gw,
    const float* __restrict__ gbias,
    unsigned int* __restrict__ tsupb,
    uint4* __restrict__ fragtab,
    float* __restrict__ u_pg,
    float* __restrict__ loc2g)
{
  const int tid = threadIdx.x;
  const int blk = blockIdx.x;

  if (blk >= 256){
    if (blk < 264){
      int local = blk - 256;
      int k = local*16 + (tid >> 4), e0 = (tid & 15)*4;
      float a0=0.f, a1=0.f, a2=0.f, a3=0.f;
      for (int d = 0; d < 64; ++d){
        float ev = emb[k*64 + d];
        float4 wv = *reinterpret_cast<const float4*>(acc_w + d*64 + e0);
        a0 += ev*wv.x; a1 += ev*wv.y; a2 += ev*wv.z; a3 += ev*wv.w;
      }
      tsupb[k*32 + (e0 >> 1)]     = cvt_pk_bf16(a0*RECIP129, a1*RECIP129);
      tsupb[k*32 + (e0 >> 1) + 1] = cvt_pk_bf16(a2*RECIP129, a3*RECIP129);
    } else {
      int lane = tid & 63, r = lane & 15, h = lane >> 4;
      #pragma unroll
      for (int i = 0; i < 4; ++i){
        int f = (tid >> 6) + i*4;
        int layer = f >> 3, nt = (f >> 1) & 3, kc = f & 1;
        float sc = layer ? 0.5f : 1.0f;
        const float* p0 = gw + layer*4096 + (nt*16 + r)*64 + kc*32 + h*8;
        float4 a = *reinterpret_cast<const float4*>(p0);
        float4 c = *reinterpret_cast<const float4*>(p0 + 4);
        uint4 v;
        v.x = cvt_pk_bf16(sc*a.x, sc*a.y); v.y = cvt_pk_bf16(sc*a.z, sc*a.w);
        v.z = cvt_pk_bf16(sc*c.x, sc*c.y); v.w = cvt_pk_bf16(sc*c.z, sc*c.w);
        fragtab[f*64 + lane] = v;
      }
    }
    return;
  }

  // ---------------- perb: 16 b's, histogram + MFMA chain ----------------
  __shared__ int hist[16*128];
  __shared__ __align__(16) unsigned int cbf[16*64];
  __shared__ __align__(16) unsigned short srows[16*64];
  __shared__ __align__(16) unsigned short lrows[16*64];
  const int w = tid >> 6, lane = tid & 63;
  const int r = lane & 15, h = lane >> 4;
  const int bbase = blk * 16;
  const int n = w*16 + h*4;
  const unsigned int swzr = (unsigned)(r & 7) << 4;

  #pragma unroll
  for (int i = 0; i < 8; ++i) hist[tid*8 + i] = 0;

  bf16x8 af_s[4], af_q[4], aw[2], l0f[2], l1f[2];
  {
    float vs[8], vq[8];
    #pragma unroll
    for (int kc = 0; kc < 4; ++kc){
      #pragma unroll
      for (int j = 0; j < 8; ++j){
        float x = emb[(kc*32 + h*8 + j)*64 + w*16 + r];
        vs[j] = x; vq[j] = x*x;
      }
      af_s[kc] = pack8(vs);
      af_q[kc] = pack8(vq);
    }
    #pragma unroll
    for (int kc = 0; kc < 2; ++kc){
      #pragma unroll
      for (int j = 0; j < 8; ++j)
        vs[j] = acc_w[(kc*32 + h*8 + j)*64 + w*16 + r] * RECIP129;
      aw[kc] = pack8(vs);
      const float* p0 = lw + (w*16 + r)*64 + kc*32 + h*8;
      float4 a = *reinterpret_cast<const float4*>(p0);
      float4 c = *reinterpret_cast<const float4*>(p0 + 4);
      float t0[8] = {a.x,a.y,a.z,a.w,c.x,c.y,c.z,c.w};
      l0f[kc] = pack8(t0);
      a = *reinterpret_cast<const float4*>(p0 + 4096);
      c = *reinterpret_cast<const float4*>(p0 + 4100);
      float t1[8] = {a.x,a.y,a.z,a.w,c.x,c.y,c.z,c.w};
      l1f[kc] = pack8(t1);
    }
  }
  float accb[4], lb0v[4], bias05[4];
  #pragma unroll
  for (int reg = 0; reg < 4; ++reg){
    accb[reg]   = acc_b[n + reg];
    lb0v[reg]   = lb[n + reg];
    bias05[reg] = 0.5f*(lb[64 + n + reg] + gbias[64 + n + reg]);
  }

  __syncthreads();
  {
    int b_l = tid >> 4, l0 = (tid & 15) * 8;
    const int* cp = cat + (bbase + b_l)*128 + l0;
    int4 i0 = *reinterpret_cast<const int4*>(cp);
    int4 i1 = *reinterpret_cast<const int4*>(cp + 4);
    atomicAdd(&hist[b_l*128 + i0.x], 1); atomicAdd(&hist[b_l*128 + i0.y], 1);
    atomicAdd(&hist[b_l*128 + i0.z], 1); atomicAdd(&hist[b_l*128 + i0.w], 1);
    atomicAdd(&hist[b_l*128 + i1.x], 1); atomicAdd(&hist[b_l*128 + i1.y], 1);
    atomicAdd(&hist[b_l*128 + i1.z], 1); atomicAdd(&hist[b_l*128 + i1.w], 1);
  }
  __syncthreads();
  {
    int b_l = tid >> 4, c0 = (tid & 15) * 8;
    float f[8];
    #pragma unroll
    for (int i = 0; i < 8; ++i) f[i] = (float)hist[b_l*128 + c0 + i];
    uint4 v;
    v.x = cvt_pk_bf16(f[0], f[1]); v.y = cvt_pk_bf16(f[2], f[3]);
    v.z = cvt_pk_bf16(f[4], f[5]); v.w = cvt_pk_bf16(f[6], f[7]);
    *reinterpret_cast<uint4*>((char*)cbf + b_l*256 + ((unsigned)(c0*2) ^ ((unsigned)(b_l & 7) << 4))) = v;
  }
  __syncthreads();

  const char* crow = (const char*)cbf + r*256;
  f32x4 acc_s = {0,0,0,0}, acc_q = {0,0,0,0};
  #pragma unroll
  for (int kc = 0; kc < 4; ++kc){
    bf16x8 cf = __builtin_bit_cast(bf16x8,
        *reinterpret_cast<const uint4*>(crow + ((unsigned)(kc*64 + h*16) ^ swzr)));
    acc_s = __builtin_amdgcn_mfma_f32_16x16x32_bf16(af_s[kc], cf, acc_s, 0, 0, 0);
    acc_q = __builtin_amdgcn_mfma_f32_16x16x32_bf16(af_q[kc], cf, acc_q, 0, 0, 0);
  }

  char* srow = (char*)srows + r*128;
  char* lrow = (char*)lrows + r*128;
  const unsigned int off = ((unsigned)(w*32 + h*8)) ^ swzr;
  {
    u32x2 ps, pl;
    ps[0] = cvt_pk_bf16(acc_s[0], acc_s[1]);
    ps[1] = cvt_pk_bf16(acc_s[2], acc_s[3]);
    float l0 = 0.5f*(acc_s[0]*acc_s[0] - acc_q[0]);
    float l1 = 0.5f*(acc_s[1]*acc_s[1] - acc_q[1]);
    float l2v = 0.5f*(acc_s[2]*acc_s[2] - acc_q[2]);
    float l3 = 0.5f*(acc_s[3]*acc_s[3] - acc_q[3]);
    pl[0] = cvt_pk_bf16(l0, l1); pl[1] = cvt_pk_bf16(l2v, l3);
    *reinterpret_cast<u32x2*>(srow + off) = ps;
    *reinterpret_cast<u32x2*>(lrow + off) = pl;
  }
  __syncthreads();

  f32x4 acc_u; acc_u[0]=accb[0]; acc_u[1]=accb[1]; acc_u[2]=accb[2]; acc_u[3]=accb[3];
  f32x4 acc_h = {0,0,0,0};
  #pragma unroll
  for (int kc = 0; kc < 2; ++kc){
    unsigned o = ((unsigned)(kc*64 + h*16)) ^ swzr;
    bf16x8 sb = __builtin_bit_cast(bf16x8, *reinterpret_cast<const uint4*>((char*)srows + r*128 + o));
    bf16x8 lf = __builtin_bit_cast(bf16x8, *reinterpret_cast<const uint4*>((char*)lrows + r*128 + o));
    acc_u = __builtin_amdgcn_mfma_f32_16x16x32_bf16(aw[kc],  sb, acc_u, 0, 0, 0);
    acc_h = __builtin_amdgcn_mfma_f32_16x16x32_bf16(l0f[kc], lf, acc_h, 0, 0, 0);
  }
  {
    float4 st; st.x = acc_u[0]; st.y = acc_u[1]; st.z = acc_u[2]; st.w = acc_u[3];
    *reinterpret_cast<float4*>(u_pg + (size_t)(bbase + r)*64 + n) = st;
  }
  __syncthreads();
  {
    u32x2 ph;
    ph[0] = cvt_pk_bf16(fmaxf(acc_h[0] + lb0v[0], 0.f), fmaxf(acc_h[1] + lb0v[1], 0.f));
    ph[1] = cvt_pk_bf16(fmaxf(acc_h[2] + lb0v[2], 0.f), fmaxf(acc_h[3] + lb0v[3], 0.f));
    *reinterpret_cast<u32x2*>(lrow + off) = ph;
  }
  __syncthreads();

  f32x4 acc2 = {0,0,0,0};
  #pragma unroll
  for (int kc = 0; kc < 2; ++kc){
    unsigned o = ((unsigned)(kc*64 + h*16)) ^ swzr;
    bf16x8 hf = __builtin_bit_cast(bf16x8, *reinterpret_cast<const uint4*>((char*)lrows + r*128 + o));
    acc2 = __builtin_amdgcn_mfma_f32_16x16x32_bf16(l1f[kc], hf, acc2, 0, 0, 0);
  }
  {
    float4 st;
    st.x = 0.5f*acc2[0] + bias05[0]; st.y = 0.5f*acc2[1] + bias05[1];
    st.z = 0.5f*acc2[2] + bias05[2]; st.w = 0.5f*acc2[3] + bias05[3];
    *reinterpret_cast<float4*>(loc2g + (size_t)(bbase + r)*64 + n) = st;
  }
}

// ---------------- kernel B: per-(b,l) 2-layer MLP, VGPR-dieted --------------
__global__ __launch_bounds__(256, 4) void fused_kernel(
    const int*          __restrict__ cat,
    const unsigned int* __restrict__ tsupb,
    const float*        __restrict__ u_pg,
    const float*        __restrict__ loc2g,
    const uint4*        __restrict__ fragtab,
    const float*        __restrict__ gbias,
    float*              __restrict__ out)
{
  __shared__ __align__(16) unsigned short gbuf[4][16*64];  // 8 KB g1 rows only

  const int tid = threadIdx.x, wid = tid >> 6, lane = tid & 63;
  const int b = blockIdx.x*4 + wid;
  const int r = lane & 15, h = lane >> 4;

  int k0 = cat[b*128 + lane];
  int k1 = cat[b*128 + 64 + lane];

  float uf[16];
  #pragma unroll
  for (int kc = 0; kc < 2; ++kc){
    const float* up = u_pg + (size_t)b*64 + kc*32 + h*8;
    float4 a = *reinterpret_cast<const float4*>(up);
    float4 c = *reinterpret_cast<const float4*>(up + 4);
    uf[kc*8+0]=a.x; uf[kc*8+1]=a.y; uf[kc*8+2]=a.z; uf[kc*8+3]=a.w;
    uf[kc*8+4]=c.x; uf[kc*8+5]=c.y; uf[kc*8+6]=c.z; uf[kc*8+7]=c.w;
  }
  f32x4 c2i[4], gb0f[4];
  #pragma unroll
  for (int mt = 0; mt < 4; ++mt){
    float4 lv = *reinterpret_cast<const float4*>(loc2g + (size_t)b*64 + mt*16 + h*4);
    f32x4 t; t[0]=lv.x; t[1]=lv.y; t[2]=lv.z; t[3]=lv.w;
    c2i[mt] = t;
    float4 gv = *reinterpret_cast<const float4*>(gbias + mt*16 + h*4);
    f32x4 g; g[0]=gv.x; g[1]=gv.y; g[2]=gv.z; g[3]=gv.w;
    gb0f[mt] = g;
  }

  char* myrowW = (char*)&gbuf[wid][0] + r*128;
  const unsigned int rsw8 = (unsigned)(r & 7) << 4;

  for (int tl = 0; tl < 8; ++tl){
    const int rowbase = b*128 + tl*16;
    int kk = __shfl(tl < 4 ? k0 : k1, (tl & 3)*16 + r);

    // A0: g0 = relu(u + tsup[kk])   (direct from L1-resident tsupb)
    const uint4* trow = reinterpret_cast<const uint4*>(tsupb + kk*32);
    bf16x8 a0[2];
    #pragma unroll
    for (int kc = 0; kc < 2; ++kc){
      uint4 wv = trow[kc*4 + h];
      unsigned int ow[4];
      const unsigned int* wp = &wv.x;
      #pragma unroll
      for (int q = 0; q < 4; ++q){
        unsigned int wq = wp[q];
        float lo = fmaxf(__uint_as_float(wq << 16)         + uf[kc*8 + 2*q],     0.f);
        float hi = fmaxf(__uint_as_float(wq & 0xffff0000u) + uf[kc*8 + 2*q + 1], 0.f);
        ow[q] = cvt_pk_bf16(lo, hi);
      }
      uint4 packed; packed.x=ow[0]; packed.y=ow[1]; packed.z=ow[2]; packed.w=ow[3];
      a0[kc] = __builtin_bit_cast(bf16x8, packed);
    }

    // layer 1 transposed (w0 frags re-read from L1-resident fragtab)
    f32x4 acc1[4];
    #pragma unroll
    for (int nt = 0; nt < 4; ++nt) acc1[nt] = gb0f[nt];
    #pragma unroll
    for (int kc = 0; kc < 2; ++kc)
      #pragma unroll
      for (int nt = 0; nt < 4; ++nt){
        bf16x8 w0f = __builtin_bit_cast(bf16x8, fragtab[(nt*2 + kc)*64 + lane]);
        acc1[nt] = __builtin_amdgcn_mfma_f32_16x16x32_bf16(w0f, a0[kc], acc1[nt], 0, 0, 0);
      }

    #pragma unroll
    for (int nt = 0; nt < 4; ++nt){
      u32x2 p;
      p[0] = cvt_pk_bf16(fmaxf(acc1[nt][0], 0.f), fmaxf(acc1[nt][1], 0.f));
      p[1] = cvt_pk_bf16(fmaxf(acc1[nt][2], 0.f), fmaxf(acc1[nt][3], 0.f));
      *reinterpret_cast<u32x2*>(myrowW + ((unsigned)(nt*32 + h*8) ^ rsw8)) = p;
    }

    bf16x8 a1[2];
    #pragma unroll
    for (int kc = 0; kc < 2; ++kc)
      a1[kc] = __builtin_bit_cast(bf16x8,
                 *reinterpret_cast<const uint4*>(myrowW + ((unsigned)(kc*64 + h*16) ^ rsw8)));

    // layer 2 transposed (w1 frags re-read from L1-resident fragtab)
    f32x4 acc2[4];
    #pragma unroll
    for (int mt = 0; mt < 4; ++mt) acc2[mt] = c2i[mt];
    #pragma unroll
    for (int kc = 0; kc < 2; ++kc)
      #pragma unroll
      for (int mt = 0; mt < 4; ++mt){
        bf16x8 w1f = __builtin_bit_cast(bf16x8, fragtab[(8 + mt*2 + kc)*64 + lane]);
        acc2[mt] = __builtin_amdgcn_mfma_f32_16x16x32_bf16(w1f, a1[kc], acc2[mt], 0, 0, 0);
      }

    float* orow = out + (size_t)(rowbase + r)*64 + h*4;
    #pragma unroll
    for (int mt = 0; mt < 4; ++mt){
      float4 st;
      st.x = acc2[mt][0]; st.y = acc2[mt][1];
      st.z = acc2[mt][2]; st.w = acc2[mt][3];
      *reinterpret_cast<float4*>(orow + mt*16) = st;
    }
  }
}

extern "C" void kernel_launch(void* const* d_in, const int* in_sizes, int n_in,
                              void* d_out, int out_size, void* d_ws, size_t ws_size,
                              hipStream_t stream) {
  const int*   cat   = (const int*)  d_in[0];
  const float* emb   = (const float*)d_in[1];
  const float* acc_w = (const float*)d_in[2];
  const float* acc_b = (const float*)d_in[3];
  const float* gw    = (const float*)d_in[4];
  const float* gb    = (const float*)d_in[5];
  const float* lw    = (const float*)d_in[6];
  const float* lb    = (const float*)d_in[7];
  float* out = (float*)d_out;

  const int B = in_sizes[0] / 128;            // 4096

  float* ws           = (float*)d_ws;
  unsigned int* tsupb = (unsigned int*)ws;    // 128*32 u32
  uint4* fragtab      = (uint4*)(ws + 4096);  // 16*64 uint4
  float* u_pg         = ws + 8192;            // B*64
  float* loc2g        = u_pg + (size_t)B*64;  // B*64

  hipLaunchKernelGGL(combined_kernel, dim3(265), dim3(256), 0, stream,
                     cat, emb, acc_w, acc_b, lw, lb, gw, gb,
                     tsupb, fragtab, u_pg, loc2g);
  hipLaunchKernelGGL(fused_kernel, dim3(B/4), dim3(256), 0, stream,
                     cat, tsupb, u_pg, loc2g, fragtab, gb, out);
}

// Round 15
// 35.443 us; speedup vs baseline: 1.4647x; 1.4647x over previous
//
#include <hip/hip_runtime.h>
#include <hip/hip_bf16.h>

// CatEmbedder: B=4096, L=128, D=64, PROBE=1 -> 1/129, ALPHA=0.5
// Histogram formulation: C[b,k] = count of k in idx[b,:]  (<=128, exact bf16)
//   s[b]  = C[b]@emb,  sq[b] = C[b]@emb^2        (MFMA, transposed form)
//   u[b]  = (s[b]@acc_w)/129 + acc_b             (MFMA)
//   loc0  = 0.5*(s^2 - sq); loc2 = MLP(loc0)     (MFMA)
//   g0    = relu(u[b] + tsup[idx]); g2 = MLP(g0) (MFMA, transposed)
//   out   = (0.5*W1)·g1 + 0.5*(gb1 + lb1 + loc2) [prescaled]
// R15: single-variable occupancy test vs R10 — weight frags moved from
// 64 VGPRs to a 16KB LDS stage (ds_read_b128 at each MFMA), launch_bounds
// (256,4). Everything else identical to R10 (best, 35.9us).

typedef __attribute__((ext_vector_type(8))) short bf16x8;
typedef __attribute__((ext_vector_type(4))) float f32x4;
typedef __attribute__((ext_vector_type(2))) unsigned int u32x2;

#define RECIP129 (1.0f/129.0f)

static __device__ __forceinline__ unsigned int cvt_pk_bf16(float lo, float hi){
  unsigned int r;
  asm("v_cvt_pk_bf16_f32 %0, %1, %2" : "=v"(r) : "v"(lo), "v"(hi));
  return r;
}
static __device__ __forceinline__ bf16x8 pack8(const float* v){
  uint4 p;
  p.x = cvt_pk_bf16(v[0], v[1]); p.y = cvt_pk_bf16(v[2], v[3]);
  p.z = cvt_pk_bf16(v[4], v[5]); p.w = cvt_pk_bf16(v[6], v[7]);
  return __builtin_bit_cast(bf16x8, p);
}

// ---------------- kernel A: perb (0-255) | tsupb (256-263) | gwfrag (264) ---
__global__ __launch_bounds__(256) void combined_kernel(
    const int*   __restrict__ cat,
    const float* __restrict__ emb,
    const float* __restrict__ acc_w,
    const float* __restrict__ acc_b,
    const float* __restrict__ lw,
    const float* __restrict__ lb,
    const float* __restrict__ gw,
    const float* __restrict__ gbias,
    unsigned int* __restrict__ tsupb,
    uint4* __restrict__ fragtab,
    float* __restrict__ u_pg,
    float* __restrict__ loc2g)
{
  const int tid = threadIdx.x;
  const int blk = blockIdx.x;

  if (blk >= 256){
    if (blk < 264){
      int local = blk - 256;
      int k = local*16 + (tid >> 4), e0 = (tid & 15)*4;
      float a0=0.f, a1=0.f, a2=0.f, a3=0.f;
      for (int d = 0; d < 64; ++d){
        float ev = emb[k*64 + d];
        float4 wv = *reinterpret_cast<const float4*>(acc_w + d*64 + e0);
        a0 += ev*wv.x; a1 += ev*wv.y; a2 += ev*wv.z; a3 += ev*wv.w;
      }
      tsupb[k*32 + (e0 >> 1)]     = cvt_pk_bf16(a0*RECIP129, a1*RECIP129);
      tsupb[k*32 + (e0 >> 1) + 1] = cvt_pk_bf16(a2*RECIP129, a3*RECIP129);
    } else {
      int lane = tid & 63, r = lane & 15, h = lane >> 4;
      #pragma unroll
      for (int i = 0; i < 4; ++i){
        int f = (tid >> 6) + i*4;
        int layer = f >> 3, nt = (f >> 1) & 3, kc = f & 1;
        float sc = layer ? 0.5f : 1.0f;
        const float* p0 = gw + layer*4096 + (nt*16 + r)*64 + kc*32 + h*8;
        float4 a = *reinterpret_cast<const float4*>(p0);
        float4 c = *reinterpret_cast<const float4*>(p0 + 4);
        uint4 v;
        v.x = cvt_pk_bf16(sc*a.x, sc*a.y); v.y = cvt_pk_bf16(sc*a.z, sc*a.w);
        v.z = cvt_pk_bf16(sc*c.x, sc*c.y); v.w = cvt_pk_bf16(sc*c.z, sc*c.w);
        fragtab[f*64 + lane] = v;
      }
    }
    return;
  }

  // ---------------- perb: 16 b's, histogram + MFMA chain ----------------
  __shared__ int hist[16*128];
  __shared__ __align__(16) unsigned int cbf[16*64];
  __shared__ __align__(16) unsigned short srows[16*64];
  __shared__ __align__(16) unsigned short lrows[16*64];
  const int w = tid >> 6, lane = tid & 63;
  const int r = lane & 15, h = lane >> 4;
  const int bbase = blk * 16;
  const int n = w*16 + h*4;
  const unsigned int swzr = (unsigned)(r & 7) << 4;

  #pragma unroll
  for (int i = 0; i < 8; ++i) hist[tid*8 + i] = 0;

  bf16x8 af_s[4], af_q[4], aw[2], l0f[2], l1f[2];
  {
    float vs[8], vq[8];
    #pragma unroll
    for (int kc = 0; kc < 4; ++kc){
      #pragma unroll
      for (int j = 0; j < 8; ++j){
        float x = emb[(kc*32 + h*8 + j)*64 + w*16 + r];
        vs[j] = x; vq[j] = x*x;
      }
      af_s[kc] = pack8(vs);
      af_q[kc] = pack8(vq);
    }
    #pragma unroll
    for (int kc = 0; kc < 2; ++kc){
      #pragma unroll
      for (int j = 0; j < 8; ++j)
        vs[j] = acc_w[(kc*32 + h*8 + j)*64 + w*16 + r] * RECIP129;
      aw[kc] = pack8(vs);
      const float* p0 = lw + (w*16 + r)*64 + kc*32 + h*8;
      float4 a = *reinterpret_cast<const float4*>(p0);
      float4 c = *reinterpret_cast<const float4*>(p0 + 4);
      float t0[8] = {a.x,a.y,a.z,a.w,c.x,c.y,c.z,c.w};
      l0f[kc] = pack8(t0);
      a = *reinterpret_cast<const float4*>(p0 + 4096);
      c = *reinterpret_cast<const float4*>(p0 + 4100);
      float t1[8] = {a.x,a.y,a.z,a.w,c.x,c.y,c.z,c.w};
      l1f[kc] = pack8(t1);
    }
  }
  float accb[4], lb0v[4], bias05[4];
  #pragma unroll
  for (int reg = 0; reg < 4; ++reg){
    accb[reg]   = acc_b[n + reg];
    lb0v[reg]   = lb[n + reg];
    bias05[reg] = 0.5f*(lb[64 + n + reg] + gbias[64 + n + reg]);
  }

  __syncthreads();
  {
    int b_l = tid >> 4, l0 = (tid & 15) * 8;
    const int* cp = cat + (bbase + b_l)*128 + l0;
    int4 i0 = *reinterpret_cast<const int4*>(cp);
    int4 i1 = *reinterpret_cast<const int4*>(cp + 4);
    atomicAdd(&hist[b_l*128 + i0.x], 1); atomicAdd(&hist[b_l*128 + i0.y], 1);
    atomicAdd(&hist[b_l*128 + i0.z], 1); atomicAdd(&hist[b_l*128 + i0.w], 1);
    atomicAdd(&hist[b_l*128 + i1.x], 1); atomicAdd(&hist[b_l*128 + i1.y], 1);
    atomicAdd(&hist[b_l*128 + i1.z], 1); atomicAdd(&hist[b_l*128 + i1.w], 1);
  }
  __syncthreads();
  {
    int b_l = tid >> 4, c0 = (tid & 15) * 8;
    float f[8];
    #pragma unroll
    for (int i = 0; i < 8; ++i) f[i] = (float)hist[b_l*128 + c0 + i];
    uint4 v;
    v.x = cvt_pk_bf16(f[0], f[1]); v.y = cvt_pk_bf16(f[2], f[3]);
    v.z = cvt_pk_bf16(f[4], f[5]); v.w = cvt_pk_bf16(f[6], f[7]);
    *reinterpret_cast<uint4*>((char*)cbf + b_l*256 + ((unsigned)(c0*2) ^ ((unsigned)(b_l & 7) << 4))) = v;
  }
  __syncthreads();

  const char* crow = (const char*)cbf + r*256;
  f32x4 acc_s = {0,0,0,0}, acc_q = {0,0,0,0};
  #pragma unroll
  for (int kc = 0; kc < 4; ++kc){
    bf16x8 cf = __builtin_bit_cast(bf16x8,
        *reinterpret_cast<const uint4*>(crow + ((unsigned)(kc*64 + h*16) ^ swzr)));
    acc_s = __builtin_amdgcn_mfma_f32_16x16x32_bf16(af_s[kc], cf, acc_s, 0, 0, 0);
    acc_q = __builtin_amdgcn_mfma_f32_16x16x32_bf16(af_q[kc], cf, acc_q, 0, 0, 0);
  }

  char* srow = (char*)srows + r*128;
  char* lrow = (char*)lrows + r*128;
  const unsigned int off = ((unsigned)(w*32 + h*8)) ^ swzr;
  {
    u32x2 ps, pl;
    ps[0] = cvt_pk_bf16(acc_s[0], acc_s[1]);
    ps[1] = cvt_pk_bf16(acc_s[2], acc_s[3]);
    float l0 = 0.5f*(acc_s[0]*acc_s[0] - acc_q[0]);
    float l1 = 0.5f*(acc_s[1]*acc_s[1] - acc_q[1]);
    float l2v = 0.5f*(acc_s[2]*acc_s[2] - acc_q[2]);
    float l3 = 0.5f*(acc_s[3]*acc_s[3] - acc_q[3]);
    pl[0] = cvt_pk_bf16(l0, l1); pl[1] = cvt_pk_bf16(l2v, l3);
    *reinterpret_cast<u32x2*>(srow + off) = ps;
    *reinterpret_cast<u32x2*>(lrow + off) = pl;
  }
  __syncthreads();

  f32x4 acc_u; acc_u[0]=accb[0]; acc_u[1]=accb[1]; acc_u[2]=accb[2]; acc_u[3]=accb[3];
  f32x4 acc_h = {0,0,0,0};
  #pragma unroll
  for (int kc = 0; kc < 2; ++kc){
    unsigned o = ((unsigned)(kc*64 + h*16)) ^ swzr;
    bf16x8 sb = __builtin_bit_cast(bf16x8, *reinterpret_cast<const uint4*>((char*)srows + r*128 + o));
    bf16x8 lf = __builtin_bit_cast(bf16x8, *reinterpret_cast<const uint4*>((char*)lrows + r*128 + o));
    acc_u = __builtin_amdgcn_mfma_f32_16x16x32_bf16(aw[kc],  sb, acc_u, 0, 0, 0);
    acc_h = __builtin_amdgcn_mfma_f32_16x16x32_bf16(l0f[kc], lf, acc_h, 0, 0, 0);
  }
  {
    float4 st; st.x = acc_u[0]; st.y = acc_u[1]; st.z = acc_u[2]; st.w = acc_u[3];
    *reinterpret_cast<float4*>(u_pg + (size_t)(bbase + r)*64 + n) = st;
  }
  __syncthreads();
  {
    u32x2 ph;
    ph[0] = cvt_pk_bf16(fmaxf(acc_h[0] + lb0v[0], 0.f), fmaxf(acc_h[1] + lb0v[1], 0.f));
    ph[1] = cvt_pk_bf16(fmaxf(acc_h[2] + lb0v[2], 0.f), fmaxf(acc_h[3] + lb0v[3], 0.f));
    *reinterpret_cast<u32x2*>(lrow + off) = ph;
  }
  __syncthreads();

  f32x4 acc2 = {0,0,0,0};
  #pragma unroll
  for (int kc = 0; kc < 2; ++kc){
    unsigned o = ((unsigned)(kc*64 + h*16)) ^ swzr;
    bf16x8 hf = __builtin_bit_cast(bf16x8, *reinterpret_cast<const uint4*>((char*)lrows + r*128 + o));
    acc2 = __builtin_amdgcn_mfma_f32_16x16x32_bf16(l1f[kc], hf, acc2, 0, 0, 0);
  }
  {
    float4 st;
    st.x = 0.5f*acc2[0] + bias05[0]; st.y = 0.5f*acc2[1] + bias05[1];
    st.z = 0.5f*acc2[2] + bias05[2]; st.w = 0.5f*acc2[3] + bias05[3];
    *reinterpret_cast<float4*>(loc2g + (size_t)(bbase + r)*64 + n) = st;
  }
}

// ---------------- kernel B: per-(b,l) 2-layer MLP (weights in LDS) ----------
__global__ __launch_bounds__(256, 4) void fused_kernel(
    const int*          __restrict__ cat,
    const unsigned int* __restrict__ tsupb,
    const float*        __restrict__ u_pg,
    const float*        __restrict__ loc2g,
    const uint4*        __restrict__ fragtab,
    const float*        __restrict__ gbias,
    float*              __restrict__ out)
{
  __shared__ __align__(16) unsigned short ts[128*72];      // 18 KB tsup, swizzled
  __shared__ __align__(16) unsigned short gbuf[4][16*64];  // 8 KB g1 rows
  __shared__ __align__(16) uint4 wlds[16*64];              // 16 KB weight frags

  const int tid = threadIdx.x, wid = tid >> 6, lane = tid & 63;
  const int b = blockIdx.x*4 + wid;
  const int r = lane & 15, h = lane >> 4;

  // stage tsup (bf16) -> LDS, swizzled 16B blocks
  {
    int k = tid >> 1, half = tid & 1;
    const uint4* src = reinterpret_cast<const uint4*>(tsupb) + k*8 + half*4;
    char* rowp = (char*)&ts[k*72];
    unsigned int swz = (unsigned)(k & 3) << 4;
    #pragma unroll
    for (int i = 0; i < 4; ++i)
      *reinterpret_cast<uint4*>(rowp + ((unsigned)(half*64 + i*16) ^ swz)) = src[i];
  }
  // stage weight frags -> LDS (4 coalesced uint4 loads per thread)
  #pragma unroll
  for (int i = 0; i < 4; ++i)
    wlds[i*256 + tid] = fragtab[i*256 + tid];

  int k0 = cat[b*128 + lane];
  int k1 = cat[b*128 + 64 + lane];

  float uf[16];
  #pragma unroll
  for (int kc = 0; kc < 2; ++kc){
    const float* up = u_pg + (size_t)b*64 + kc*32 + h*8;
    float4 a = *reinterpret_cast<const float4*>(up);
    float4 c = *reinterpret_cast<const float4*>(up + 4);
    uf[kc*8+0]=a.x; uf[kc*8+1]=a.y; uf[kc*8+2]=a.z; uf[kc*8+3]=a.w;
    uf[kc*8+4]=c.x; uf[kc*8+5]=c.y; uf[kc*8+6]=c.z; uf[kc*8+7]=c.w;
  }
  f32x4 c2i[4], gb0f[4];
  #pragma unroll
  for (int mt = 0; mt < 4; ++mt){
    float4 lv = *reinterpret_cast<const float4*>(loc2g + (size_t)b*64 + mt*16 + h*4);
    f32x4 t; t[0]=lv.x; t[1]=lv.y; t[2]=lv.z; t[3]=lv.w;
    c2i[mt] = t;
    float4 gv = *reinterpret_cast<const float4*>(gbias + mt*16 + h*4);
    f32x4 g; g[0]=gv.x; g[1]=gv.y; g[2]=gv.z; g[3]=gv.w;
    gb0f[mt] = g;
  }

  __syncthreads();

  char* myrowW = (char*)&gbuf[wid][0] + r*128;
  const unsigned int rsw8 = (unsigned)(r & 7) << 4;

  for (int tl = 0; tl < 8; ++tl){
    const int rowbase = b*128 + tl*16;
    int kk = __shfl(tl < 4 ? k0 : k1, (tl & 3)*16 + r);

    const char* trow = (const char*)&ts[kk*72];
    const unsigned int ksw = (unsigned)(kk & 3) << 4;
    bf16x8 a0[2];
    #pragma unroll
    for (int kc = 0; kc < 2; ++kc){
      uint4 wv = *reinterpret_cast<const uint4*>(trow + ((unsigned)(kc*64 + h*16) ^ ksw));
      unsigned int ow[4];
      const unsigned int* wp = &wv.x;
      #pragma unroll
      for (int q = 0; q < 4; ++q){
        unsigned int wq = wp[q];
        float lo = fmaxf(__uint_as_float(wq << 16)         + uf[kc*8 + 2*q],     0.f);
        float hi = fmaxf(__uint_as_float(wq & 0xffff0000u) + uf[kc*8 + 2*q + 1], 0.f);
        ow[q] = cvt_pk_bf16(lo, hi);
      }
      uint4 packed; packed.x=ow[0]; packed.y=ow[1]; packed.z=ow[2]; packed.w=ow[3];
      a0[kc] = __builtin_bit_cast(bf16x8, packed);
    }

    // layer 1 transposed (w0 frags from LDS)
    f32x4 acc1[4];
    #pragma unroll
    for (int nt = 0; nt < 4; ++nt) acc1[nt] = gb0f[nt];
    #pragma unroll
    for (int kc = 0; kc < 2; ++kc)
      #pragma unroll
      for (int nt = 0; nt < 4; ++nt){
        bf16x8 w0f = __builtin_bit_cast(bf16x8, wlds[(nt*2 + kc)*64 + lane]);
        acc1[nt] = __builtin_amdgcn_mfma_f32_16x16x32_bf16(w0f, a0[kc], acc1[nt], 0, 0, 0);
      }

    #pragma unroll
    for (int nt = 0; nt < 4; ++nt){
      u32x2 p;
      p[0] = cvt_pk_bf16(fmaxf(acc1[nt][0], 0.f), fmaxf(acc1[nt][1], 0.f));
      p[1] = cvt_pk_bf16(fmaxf(acc1[nt][2], 0.f), fmaxf(acc1[nt][3], 0.f));
      *reinterpret_cast<u32x2*>(myrowW + ((unsigned)(nt*32 + h*8) ^ rsw8)) = p;
    }

    bf16x8 a1[2];
    #pragma unroll
    for (int kc = 0; kc < 2; ++kc)
      a1[kc] = __builtin_bit_cast(bf16x8,
                 *reinterpret_cast<const uint4*>(myrowW + ((unsigned)(kc*64 + h*16) ^ rsw8)));

    // layer 2 transposed (w1 frags from LDS; W1 pre-halved)
    f32x4 acc2[4];
    #pragma unroll
    for (int mt = 0; mt < 4; ++mt) acc2[mt] = c2i[mt];
    #pragma unroll
    for (int kc = 0; kc < 2; ++kc)
      #pragma unroll
      for (int mt = 0; mt < 4; ++mt){
        bf16x8 w1f = __builtin_bit_cast(bf16x8, wlds[(8 + mt*2 + kc)*64 + lane]);
        acc2[mt] = __builtin_amdgcn_mfma_f32_16x16x32_bf16(w1f, a1[kc], acc2[mt], 0, 0, 0);
      }

    float* orow = out + (size_t)(rowbase + r)*64 + h*4;
    #pragma unroll
    for (int mt = 0; mt < 4; ++mt){
      float4 st;
      st.x = acc2[mt][0]; st.y = acc2[mt][1];
      st.z = acc2[mt][2]; st.w = acc2[mt][3];
      *reinterpret_cast<float4*>(orow + mt*16) = st;
    }
  }
}

extern "C" void kernel_launch(void* const* d_in, const int* in_sizes, int n_in,
                              void* d_out, int out_size, void* d_ws, size_t ws_size,
                              hipStream_t stream) {
  const int*   cat   = (const int*)  d_in[0];
  const float* emb   = (const float*)d_in[1];
  const float* acc_w = (const float*)d_in[2];
  const float* acc_b = (const float*)d_in[3];
  const float* gw    = (const float*)d_in[4];
  const float* gb    = (const float*)d_in[5];
  const float* lw    = (const float*)d_in[6];
  const float* lb    = (const float*)d_in[7];
  float* out = (float*)d_out;

  const int B = in_sizes[0] / 128;            // 4096

  float* ws           = (float*)d_ws;
  unsigned int* tsupb = (unsigned int*)ws;    // 128*32 u32
  uint4* fragtab      = (uint4*)(ws + 4096);  // 16*64 uint4
  float* u_pg         = ws + 8192;            // B*64
  float* loc2g        = u_pg + (size_t)B*64;  // B*64

  hipLaunchKernelGGL(combined_kernel, dim3(265), dim3(256), 0, stream,
                     cat, emb, acc_w, acc_b, lw, lb, gw, gb,
                     tsupb, fragtab, u_pg, loc2g);
  hipLaunchKernelGGL(fused_kernel, dim3(B/4), dim3(256), 0, stream,
                     cat, tsupb, u_pg, loc2g, fragtab, gb, out);
}